// Round 5
// baseline (445.338 us; speedup 1.0000x reference)
//
#include <hip/hip_runtime.h>
#include <hip/hip_bf16.h>
#include <stdint.h>

typedef __bf16 bf16;
typedef __bf16 bf16x4 __attribute__((ext_vector_type(4)));
typedef __bf16 bf16x8 __attribute__((ext_vector_type(8)));
typedef float f32x4 __attribute__((ext_vector_type(4)));

// async global->LDS, 16B per lane. LDS dest is wave-uniform base + lane*16.
__device__ __forceinline__ void async_ld16(const void* g, void* l) {
  __builtin_amdgcn_global_load_lds(
      (__attribute__((address_space(1))) void*)(void*)(g),
      (__attribute__((address_space(3))) void*)(l), 16, 0, 0);
}

// fast f32->bf16 (round-half-up): 2 VALU ops. Values are finite, non-NaN.
__device__ __forceinline__ bf16 fast_bf16(float f) {
  uint32_t u = (__float_as_uint(f) + 0x8000u) >> 16;
  union { uint16_t s; bf16 b; } cv;
  cv.s = (uint16_t)u;
  return cv.b;
}

// pack two f32 -> bf16x2 in a u32: 2 adds + 1 v_perm_b32. (VERIFIED bit-exact;
// R2's v_cvt_pk_bf16_f32 asm replacement FAILED correctness - do not retry
// without an isolated layout probe.)
__device__ __forceinline__ uint32_t pack_bf16(float lo, float hi) {
  return __builtin_amdgcn_perm(__float_as_uint(hi) + 0x8000u,
                               __float_as_uint(lo) + 0x8000u, 0x07060302u);
}

// ---------------- cast x fp32 -> bf16 ----------------
__global__ __launch_bounds__(256) void cast_f32_bf16(const float* __restrict__ in,
                                                     bf16* __restrict__ out, int n) {
  int i = (blockIdx.x * 256 + threadIdx.x) * 4;
  if (i < n) {
    float4 f = *(const float4*)(in + i);
    uint2 o;
    o.x = pack_bf16(f.x, f.y);
    o.y = pack_bf16(f.z, f.w);
    *(uint2*)(out + i) = o;
  }
}

// ---------------- fused weight transpose-cast: Wq/Wk/Wv -> Wt, Wo -> Wot ----------------
__global__ __launch_bounds__(256) void transpose_weights(const float* __restrict__ Wq,
                                                         const float* __restrict__ Wk,
                                                         const float* __restrict__ Wv,
                                                         const float* __restrict__ Wo,
                                                         bf16* __restrict__ Wt,
                                                         bf16* __restrict__ Wot) {
  __shared__ bf16 tile[64][66];
  int z = blockIdx.z;
  const float* src = z == 0 ? Wq : (z == 1 ? Wk : (z == 2 ? Wv : Wo));
  bf16* dst = z == 0 ? Wt : (z == 1 ? Wt + 1048576 : (z == 2 ? Wt + 2097152 : Wot));
  int r0 = blockIdx.x * 64, c0 = blockIdx.y * 64;
  int t = threadIdx.x;
#pragma unroll
  for (int i = 0; i < 16; ++i) {
    int idx = t + i * 256;
    int r = idx >> 6, c = idx & 63;
    tile[r][c] = fast_bf16(src[(size_t)(r0 + r) * 1024 + (c0 + c)]);
  }
  __syncthreads();
#pragma unroll
  for (int i = 0; i < 16; ++i) {
    int idx = t + i * 256;
    int c = idx >> 6, r = idx & 63;
    dst[(size_t)(c0 + c) * 1024 + (r0 + r)] = tile[r][c];
  }
}

// ---------------- 256x128 pipelined bf16 GEMM mainloop (R4-proven) ----------------
// 8 waves (4M x 2N, per-wave 64x64), K=1024, XOR-swizzled LDS (chunk c of row r
// at position c^(r&7); all fragment reads use rows == l15 mod 8 -> conflict-free).
// Next K-step staged EARLY (phases 0-1) into the dead buffer; ONE barrier per
// K-step (issue-to-drain gap >= 2 fenced phases hides VMEM latency).
// smem layout: buf b at smem + b*24576 (A 256x64 | B 128x64).
__device__ __forceinline__ void gemm256_mainloop(const bf16* __restrict__ A,
                                                 const bf16* __restrict__ Bt,
                                                 int rowBase, int colBase,
                                                 bf16* smem, f32x4 (&acc)[4][4]) {
  int t = threadIdx.x, lane = t & 63, w = t >> 6;          // w 0..7
  int wM = w >> 1, wN = w & 1, quad = lane >> 4, l15 = lane & 15;
  int r_off = lane >> 3;
  int c_sw = (((lane & 7) ^ r_off) << 3);
  int sw = l15 & 7;

  // prologue: stage K-step 0 into buf 0 (A: 4 loads/thread, B: 2)
#pragma unroll
  for (int i = 0; i < 4; ++i) {
    int e = (w * 4 + i) * 512;
    int row = (e >> 6) + r_off;
    async_ld16(A + (size_t)(rowBase + row) * 1024 + c_sw, smem + e);
  }
#pragma unroll
  for (int i = 0; i < 2; ++i) {
    int e = (w * 2 + i) * 512;
    int row = (e >> 6) + r_off;
    async_ld16(Bt + (size_t)(colBase + row) * 1024 + c_sw, smem + 16384 + e);
  }
  __syncthreads();  // drains vmcnt: step 0 resident

  for (int kt = 0; kt < 16; ++kt) {
    int cur = kt & 1;
    const bf16* As = smem + cur * 24576;
    const bf16* Bs = As + 16384;
    bf16* Asn = smem + (cur ^ 1) * 24576;
    bf16* Bsn = Asn + 16384;
    int kn = (kt + 1) * 64;

    bf16x8 af[4], bfr[2];

    // ---- ph0: issue A-stage(kt+1); read A ks0 + B ni{0,1} ks0; 8 MFMA ----
    if (kt < 15) {
#pragma unroll
      for (int i = 0; i < 4; ++i) {
        int e = (w * 4 + i) * 512;
        int row = (e >> 6) + r_off;
        async_ld16(A + (size_t)(rowBase + row) * 1024 + (kn + c_sw), Asn + e);
      }
    }
    {
      int co = ((quad ^ sw) << 3);  // ks = 0
#pragma unroll
      for (int mi = 0; mi < 4; ++mi)
        af[mi] = *(const bf16x8*)(As + (wM * 64 + mi * 16 + l15) * 64 + co);
      bfr[0] = *(const bf16x8*)(Bs + (wN * 64 + l15) * 64 + co);
      bfr[1] = *(const bf16x8*)(Bs + (wN * 64 + 16 + l15) * 64 + co);
      asm volatile("s_waitcnt lgkmcnt(0)" ::: "memory");
      __builtin_amdgcn_sched_barrier(0);
      __builtin_amdgcn_s_setprio(1);
#pragma unroll
      for (int mi = 0; mi < 4; ++mi) {
        acc[mi][0] = __builtin_amdgcn_mfma_f32_16x16x32_bf16(af[mi], bfr[0], acc[mi][0], 0, 0, 0);
        acc[mi][1] = __builtin_amdgcn_mfma_f32_16x16x32_bf16(af[mi], bfr[1], acc[mi][1], 0, 0, 0);
      }
      __builtin_amdgcn_s_setprio(0);
    }

    // ---- ph1: issue B-stage(kt+1); read B ni{2,3} ks0; 8 MFMA ----
    if (kt < 15) {
#pragma unroll
      for (int i = 0; i < 2; ++i) {
        int e = (w * 2 + i) * 512;
        int row = (e >> 6) + r_off;
        async_ld16(Bt + (size_t)(colBase + row) * 1024 + (kn + c_sw), Bsn + e);
      }
    }
    {
      int co = ((quad ^ sw) << 3);
      bfr[0] = *(const bf16x8*)(Bs + (wN * 64 + 32 + l15) * 64 + co);
      bfr[1] = *(const bf16x8*)(Bs + (wN * 64 + 48 + l15) * 64 + co);
      asm volatile("s_waitcnt lgkmcnt(0)" ::: "memory");
      __builtin_amdgcn_sched_barrier(0);
      __builtin_amdgcn_s_setprio(1);
#pragma unroll
      for (int mi = 0; mi < 4; ++mi) {
        acc[mi][2] = __builtin_amdgcn_mfma_f32_16x16x32_bf16(af[mi], bfr[0], acc[mi][2], 0, 0, 0);
        acc[mi][3] = __builtin_amdgcn_mfma_f32_16x16x32_bf16(af[mi], bfr[1], acc[mi][3], 0, 0, 0);
      }
      __builtin_amdgcn_s_setprio(0);
    }

    // ---- ph2: read A ks1 + B ni{0,1} ks1; 8 MFMA ----
    {
      int co = (((4 + quad) ^ sw) << 3);  // ks = 1
#pragma unroll
      for (int mi = 0; mi < 4; ++mi)
        af[mi] = *(const bf16x8*)(As + (wM * 64 + mi * 16 + l15) * 64 + co);
      bfr[0] = *(const bf16x8*)(Bs + (wN * 64 + l15) * 64 + co);
      bfr[1] = *(const bf16x8*)(Bs + (wN * 64 + 16 + l15) * 64 + co);
      asm volatile("s_waitcnt lgkmcnt(0)" ::: "memory");
      __builtin_amdgcn_sched_barrier(0);
      __builtin_amdgcn_s_setprio(1);
#pragma unroll
      for (int mi = 0; mi < 4; ++mi) {
        acc[mi][0] = __builtin_amdgcn_mfma_f32_16x16x32_bf16(af[mi], bfr[0], acc[mi][0], 0, 0, 0);
        acc[mi][1] = __builtin_amdgcn_mfma_f32_16x16x32_bf16(af[mi], bfr[1], acc[mi][1], 0, 0, 0);
      }
      __builtin_amdgcn_s_setprio(0);
    }

    // ---- ph3: read B ni{2,3} ks1; 8 MFMA ----
    {
      int co = (((4 + quad) ^ sw) << 3);
      bfr[0] = *(const bf16x8*)(Bs + (wN * 64 + 32 + l15) * 64 + co);
      bfr[1] = *(const bf16x8*)(Bs + (wN * 64 + 48 + l15) * 64 + co);
      asm volatile("s_waitcnt lgkmcnt(0)" ::: "memory");
      __builtin_amdgcn_sched_barrier(0);
      __builtin_amdgcn_s_setprio(1);
#pragma unroll
      for (int mi = 0; mi < 4; ++mi) {
        acc[mi][2] = __builtin_amdgcn_mfma_f32_16x16x32_bf16(af[mi], bfr[0], acc[mi][2], 0, 0, 0);
        acc[mi][3] = __builtin_amdgcn_mfma_f32_16x16x32_bf16(af[mi], bfr[1], acc[mi][3], 0, 0, 0);
      }
      __builtin_amdgcn_s_setprio(0);
    }

    // end-of-step: all waves done reading buf[cur]; buf[cur^1] stages (issued
    // >= 2 phases ago) drain cheaply in the barrier's implicit vmcnt(0).
    __syncthreads();
  }
}

// GEMM1: X[8192,1024] @ Wqkv^T[3072,1024] -> Q/K [bh][s][d], V^T [bh][d][s].
// R4-proven pipelined mainloop; epilogues through LDS re-tiles for coalesced
// b128 stores. Grid 24x32 = 768 blocks = exactly 3 full-residency rounds.
__global__ __launch_bounds__(512, 2) void gemm_qkv(const bf16* __restrict__ X,
                                                   const bf16* __restrict__ Wt,
                                                   const float* __restrict__ bq,
                                                   const float* __restrict__ bk,
                                                   const float* __restrict__ bv,
                                                   bf16* __restrict__ Qo,
                                                   bf16* __restrict__ Ko,
                                                   bf16* __restrict__ Vto) {
  __shared__ alignas(16) bf16 smem[2 * 24576];  // 96 KB

  int t = threadIdx.x, lane = t & 63, w = t >> 6;
  int wM = w >> 1, wN = w & 1, quad = lane >> 4, l15 = lane & 15;
  int rowBase = blockIdx.y * 256, colBase = blockIdx.x * 128;

  f32x4 acc[4][4];
  f32x4 z = {0.f, 0.f, 0.f, 0.f};
#pragma unroll
  for (int mi = 0; mi < 4; ++mi)
#pragma unroll
    for (int ni = 0; ni < 4; ++ni) acc[mi][ni] = z;

  gemm256_mainloop(X, Wt, rowBase, colBase, smem, acc);

  // ---------------- epilogue (verified patterns, 256-row sizes) ----------------
  int which = colBase >> 10;  // 0:q 1:k 2:v (128-tiles never straddle)
  int baseh = (colBase & 1023) >> 6;
  int b = rowBase >> 11, s0 = rowBase & 2047;
  bf16* ep = smem;

  if (which == 2) {
    // V^T [bh][d][s]: LDS re-tile [64 d][256 s (+8 pad)], coalesced b128 stores.
#pragma unroll
    for (int hp = 0; hp < 2; ++hp) {
      __syncthreads();
      if (wN == hp) {
#pragma unroll
        for (int mi = 0; mi < 4; ++mi)
#pragma unroll
          for (int ni = 0; ni < 4; ++ni) {
            int d = ni * 16 + l15;
            float bb = bv[(colBase & 1023) + hp * 64 + d];
            int sl = wM * 64 + mi * 16 + quad * 4;
            uint2 pv;
            pv.x = pack_bf16(acc[mi][ni][0] + bb, acc[mi][ni][1] + bb);
            pv.y = pack_bf16(acc[mi][ni][2] + bb, acc[mi][ni][3] + bb);
            *(uint2*)(ep + d * 264 + sl) = pv;
          }
      }
      __syncthreads();
      int hg = baseh + hp;
#pragma unroll
      for (int it = 0; it < 4; ++it) {
        int idx = t + it * 512;
        int d = idx >> 5, c = idx & 31;
        bf16x8 vv = *(const bf16x8*)(ep + d * 264 + c * 8);
        *(bf16x8*)(Vto + (((size_t)((b << 4) + hg) << 6) + d) * 2048 + s0 + c * 8) = vv;
      }
    }
  } else {
    // Q/K [bh][s][d]: stage [256 s][64 d] (+pad), contiguous 32 KB global region.
    const float* bias = which == 0 ? bq : bk;
    bf16* dst = which == 0 ? Qo : Ko;
    float scale = which == 0 ? 0.125f * 1.44269504f : 1.0f;
#pragma unroll
    for (int hp = 0; hp < 2; ++hp) {
      __syncthreads();
      if (wN == hp) {
#pragma unroll
        for (int mi = 0; mi < 4; ++mi)
#pragma unroll
          for (int ni = 0; ni < 4; ++ni) {
            int d = ni * 16 + l15;
            float bb = bias[(colBase & 1023) + hp * 64 + d];
            int m = wM * 64 + mi * 16 + quad * 4;
#pragma unroll
            for (int r = 0; r < 4; ++r)
              ep[(m + r) * 72 + d] = fast_bf16((acc[mi][ni][r] + bb) * scale);
          }
      }
      __syncthreads();
      int hg = baseh + hp;
      bf16* gbase = dst + ((((size_t)((b << 4) + hg)) * 2048 + s0) << 6);
#pragma unroll
      for (int it = 0; it < 4; ++it) {
        int idx = t + it * 512;
        int m = idx >> 3, c = idx & 7;
        bf16x8 vv = *(const bf16x8*)(ep + m * 72 + c * 8);
        *(bf16x8*)(gbase + m * 64 + c * 8) = vv;
      }
    }
  }
}

// GEMM2 (R5): ctx[8192,1024] @ Wo^T[1024,1024] + bo -> out fp32.
// Same R4-proven pipelined 256x128 mainloop; direct fp32 epilogue.
// Grid 8x32 = 256 blocks = exactly 1/CU full residency.
__global__ __launch_bounds__(512, 2) void gemm_out(const bf16* __restrict__ Cb,
                                                   const bf16* __restrict__ Wot,
                                                   const float* __restrict__ bo,
                                                   float* __restrict__ out) {
  __shared__ alignas(16) bf16 smem[2 * 24576];  // 96 KB

  int t = threadIdx.x, lane = t & 63, w = t >> 6;
  int wM = w >> 1, wN = w & 1, quad = lane >> 4, l15 = lane & 15;
  int rowBase = blockIdx.y * 256, colBase = blockIdx.x * 128;

  f32x4 acc[4][4];
  f32x4 z = {0.f, 0.f, 0.f, 0.f};
#pragma unroll
  for (int mi = 0; mi < 4; ++mi)
#pragma unroll
    for (int ni = 0; ni < 4; ++ni) acc[mi][ni] = z;

  gemm256_mainloop(Cb, Wot, rowBase, colBase, smem, acc);

#pragma unroll
  for (int mi = 0; mi < 4; ++mi)
#pragma unroll
    for (int ni = 0; ni < 4; ++ni) {
      int n = colBase + wN * 64 + ni * 16 + l15;
      float bb = bo[n];
#pragma unroll
      for (int r = 0; r < 4; ++r) {
        int m = rowBase + wM * 64 + mi * 16 + quad * 4 + r;
        out[(size_t)m * 1024 + n] = acc[mi][ni][r] + bb;
      }
    }
}

// ---------------- flash attention: 256q blocks, 64q/wave, half-split pipeline ----
// R4 addressing (conflict-free XOR-swizzled P, 64-wide rows) + half-split exp/PV
// overlap + l via ones-B MFMA + T5 setprio (R3: 93.3 -> 87.7 us).
// R5: occupancy lever DECONFOUNDED from R1 — keep 64q/wave + all read patterns,
// single-buffer K/V with T14 reg-prefetch (global->reg at tile start, ds_write
// after the end-of-tile barrier). LDS 64->48 KB -> 3 blocks/CU = 12 waves/CU
// (+50% TLP for this VALU/latency-bound kernel; true matrix-pipe busy ~5%).
__global__ __launch_bounds__(256, 3) void attn(const bf16* __restrict__ Q,
                                               const bf16* __restrict__ Kg,
                                               const bf16* __restrict__ Vt,
                                               bf16* __restrict__ ctx) {
  __shared__ alignas(16) bf16 QPs[256 * 64];   // 32 KB: Q stage, then per-wave P
  __shared__ alignas(16) bf16 Ks[4096];        //  8 KB [key][dh] swizzled, single buf
  __shared__ alignas(16) bf16 Vs[4096];        //  8 KB [dh][key] swizzled, single buf

  int t = threadIdx.x, lane = t & 63, w = t >> 6;
  int quad = lane >> 4, l15 = lane & 15;
  int r_off = lane >> 3;
  int c_sw = (((lane & 7) ^ r_off) << 3);
  int sw = l15 & 7;
  int bh = blockIdx.x;
  int q0 = blockIdx.y * 256;
  const bf16* Qp = Q + ((size_t)bh * 2048 + q0) * 64;
  const bf16* Kp = Kg + (size_t)bh * 2048 * 64;
  const bf16* Vp = Vt + (size_t)bh * 64 * 2048;

  // prologue: stage own wave's 64 Q rows + K/V tile 0
#pragma unroll
  for (int i = 0; i < 8; ++i) {
    int e = w * 4096 + i * 512;
    int row = (e >> 6) + r_off;
    async_ld16(Qp + (size_t)row * 64 + c_sw, QPs + e);
  }
#pragma unroll
  for (int i = 0; i < 2; ++i) {
    int e = w * 1024 + i * 512;
    int row = (e >> 6) + r_off;
    async_ld16(Kp + (size_t)row * 64 + c_sw, Ks + e);
    async_ld16(Vp + (size_t)row * 2048 + c_sw, Vs + e);
  }
  __syncthreads();  // drains vmcnt: Q + tile0 ready

  // Q B-fragments: 8 x bf16x8 = 32 VGPRs (own wave's 64 rows)
  bf16x8 qf[2][4];
#pragma unroll
  for (int ks = 0; ks < 2; ++ks)
#pragma unroll
    for (int qi = 0; qi < 4; ++qi)
      qf[ks][qi] = *(const bf16x8*)(QPs + (w * 64 + qi * 16 + l15) * 64 + (((ks * 4 + quad) ^ sw) << 3));
  asm volatile("s_waitcnt lgkmcnt(0)" ::: "memory");  // qf in regs before P overwrites

  bf16* Ps = QPs + w * 4096;  // per-wave 64x64 P buffer == own Q rows (safe overlay)

  bf16 one1 = (bf16)1.0f;
  bf16x8 ones = {one1, one1, one1, one1, one1, one1, one1, one1};

  f32x4 o[4][4];
  f32x4 ol[4];
  f32x4 z = {0.f, 0.f, 0.f, 0.f};
#pragma unroll
  for (int mi = 0; mi < 4; ++mi) {
    ol[mi] = z;
#pragma unroll
    for (int ni = 0; ni < 4; ++ni) o[mi][ni] = z;
  }

  for (int kt = 0; kt < 32; ++kt) {
    // T14 reg-prefetch of next K/V tile: HBM/L2 latency (~900 cyc) hides under
    // the ~6700-cyc compute phase; consumed by ds_write after the barrier.
    bf16x8 kpre[2], vpre[2];
    if (kt < 31) {
      int kn = (kt + 1) * 64;
#pragma unroll
      for (int i = 0; i < 2; ++i) {
        int e = w * 1024 + i * 512;
        int row = (e >> 6) + r_off;
        kpre[i] = *(const bf16x8*)(Kp + (size_t)(kn + row) * 64 + c_sw);
        vpre[i] = *(const bf16x8*)(Vp + (size_t)row * 2048 + kn + c_sw);
      }
    }
    const bf16* Kc = Ks;
    const bf16* Vc = Vs;

    // ---- S^T keys 0..31 (ki=0,1) ----
    f32x4 sA[2][4];
#pragma unroll
    for (int ki = 0; ki < 2; ++ki)
#pragma unroll
      for (int qi = 0; qi < 4; ++qi) sA[ki][qi] = z;
    __builtin_amdgcn_s_setprio(1);
#pragma unroll
    for (int ks = 0; ks < 2; ++ks) {
      int co = (((ks * 4 + quad) ^ sw) << 3);
      bf16x8 kf0 = *(const bf16x8*)(Kc + (l15) * 64 + co);
      bf16x8 kf1 = *(const bf16x8*)(Kc + (16 + l15) * 64 + co);
#pragma unroll
      for (int qi = 0; qi < 4; ++qi) {
        sA[0][qi] = __builtin_amdgcn_mfma_f32_16x16x32_bf16(kf0, qf[ks][qi], sA[0][qi], 0, 0, 0);
        sA[1][qi] = __builtin_amdgcn_mfma_f32_16x16x32_bf16(kf1, qf[ks][qi], sA[1][qi], 0, 0, 0);
      }
    }
    __builtin_amdgcn_s_setprio(0);
    // exp + pack + write P half A (logical chunks 0..3, R4 swizzle)
#pragma unroll
    for (int qi = 0; qi < 4; ++qi)
#pragma unroll
      for (int ki = 0; ki < 2; ++ki) {
        float p0 = __builtin_amdgcn_exp2f(sA[ki][qi][0]);
        float p1 = __builtin_amdgcn_exp2f(sA[ki][qi][1]);
        float p2 = __builtin_amdgcn_exp2f(sA[ki][qi][2]);
        float p3 = __builtin_amdgcn_exp2f(sA[ki][qi][3]);
        uint2 pb;
        pb.x = pack_bf16(p0, p1);
        pb.y = pack_bf16(p2, p3);
        int cs = (ki * 2 + (quad >> 1)) ^ sw;
        *(uint2*)(Ps + (qi * 16 + l15) * 64 + cs * 8 + (quad & 1) * 4) = pb;
      }

    // ---- S^T keys 32..63 (ki=2,3) ----
    f32x4 sB[2][4];
#pragma unroll
    for (int ki = 0; ki < 2; ++ki)
#pragma unroll
      for (int qi = 0; qi < 4; ++qi) sB[ki][qi] = z;
    __builtin_amdgcn_s_setprio(1);
#pragma unroll
    for (int ks = 0; ks < 2; ++ks) {
      int co = (((ks * 4 + quad) ^ sw) << 3);
      bf16x8 kf2 = *(const bf16x8*)(Kc + (32 + l15) * 64 + co);
      bf16x8 kf3 = *(const bf16x8*)(Kc + (48 + l15) * 64 + co);
#pragma unroll
      for (int qi = 0; qi < 4; ++qi) {
        sB[0][qi] = __builtin_amdgcn_mfma_f32_16x16x32_bf16(kf2, qf[ks][qi], sB[0][qi], 0, 0, 0);
        sB[1][qi] = __builtin_amdgcn_mfma_f32_16x16x32_bf16(kf3, qf[ks][qi], sB[1][qi], 0, 0, 0);
      }
    }
    __builtin_amdgcn_s_setprio(0);

    asm volatile("s_waitcnt lgkmcnt(0)" ::: "memory");  // P half A visible

    // ---- PV half A (keys 0..31, ks=0) + l row-sum ----
    {
      int co = ((quad ^ sw) << 3);
      bf16x8 pf[4], vf[4];
#pragma unroll
      for (int mi = 0; mi < 4; ++mi)
        pf[mi] = *(const bf16x8*)(Ps + (mi * 16 + l15) * 64 + co);
#pragma unroll
      for (int ni = 0; ni < 4; ++ni)
        vf[ni] = *(const bf16x8*)(Vc + (ni * 16 + l15) * 64 + co);
      __builtin_amdgcn_s_setprio(1);
#pragma unroll
      for (int mi = 0; mi < 4; ++mi) {
#pragma unroll
        for (int ni = 0; ni < 4; ++ni)
          o[mi][ni] = __builtin_amdgcn_mfma_f32_16x16x32_bf16(pf[mi], vf[ni], o[mi][ni], 0, 0, 0);
        ol[mi] = __builtin_amdgcn_mfma_f32_16x16x32_bf16(pf[mi], ones, ol[mi], 0, 0, 0);
      }
      __builtin_amdgcn_s_setprio(0);
    }

    // exp + pack + write P half B (logical chunks 4..7) — overlaps PV-A MFMAs
#pragma unroll
    for (int qi = 0; qi < 4; ++qi)
#pragma unroll
      for (int ki = 0; ki < 2; ++ki) {
        float p0 = __builtin_amdgcn_exp2f(sB[ki][qi][0]);
        float p1 = __builtin_amdgcn_exp2f(sB[ki][qi][1]);
        float p2 = __builtin_amdgcn_exp2f(sB[ki][qi][2]);
        float p3 = __builtin_amdgcn_exp2f(sB[ki][qi][3]);
        uint2 pb;
        pb.x = pack_bf16(p0, p1);
        pb.y = pack_bf16(p2, p3);
        int cs = (ki * 2 + 4 + (quad >> 1)) ^ sw;
        *(uint2*)(Ps + (qi * 16 + l15) * 64 + cs * 8 + (quad & 1) * 4) = pb;
      }

    asm volatile("s_waitcnt lgkmcnt(0)" ::: "memory");  // P half B visible

    // ---- PV half B (keys 32..63, ks=1) + l row-sum ----
    {
      int co = (((4 + quad) ^ sw) << 3);
      bf16x8 pf[4], vf[4];
#pragma unroll
      for (int mi = 0; mi < 4; ++mi)
        pf[mi] = *(const bf16x8*)(Ps + (mi * 16 + l15) * 64 + co);
#pragma unroll
      for (int ni = 0; ni < 4; ++ni)
        vf[ni] = *(const bf16x8*)(Vc + (ni * 16 + l15) * 64 + co);
      __builtin_amdgcn_s_setprio(1);
#pragma unroll
      for (int mi = 0; mi < 4; ++mi) {
#pragma unroll
        for (int ni = 0; ni < 4; ++ni)
          o[mi][ni] = __builtin_amdgcn_mfma_f32_16x16x32_bf16(pf[mi], vf[ni], o[mi][ni], 0, 0, 0);
        ol[mi] = __builtin_amdgcn_mfma_f32_16x16x32_bf16(pf[mi], ones, ol[mi], 0, 0, 0);
      }
      __builtin_amdgcn_s_setprio(0);
    }

    __syncthreads();  // all waves done reading Ks/Vs (and own P) for this tile
    if (kt < 31) {
      // write phase: compiler inserts s_waitcnt vmcnt(0) for kpre/vpre (long
      // since landed); 4x ds_write_b128, contiguous -> conflict-free.
#pragma unroll
      for (int i = 0; i < 2; ++i) {
        int e = w * 1024 + i * 512;
        *(bf16x8*)(Ks + e + lane * 8) = kpre[i];
        *(bf16x8*)(Vs + e + lane * 8) = vpre[i];
      }
    }
    __syncthreads();  // next K/V tile visible to all waves
  }

  // epilogue: ol[mi][r] = l for query mi*16+quad*4+r (uniform across l15)
  int b = bh >> 4, h = bh & 15;
#pragma unroll
  for (int mi = 0; mi < 4; ++mi) {
    float rl[4];
#pragma unroll
    for (int r = 0; r < 4; ++r) rl[r] = 1.0f / ol[mi][r];
#pragma unroll
    for (int ni = 0; ni < 4; ++ni) {
      int col = h * 64 + ni * 16 + l15;
#pragma unroll
      for (int r = 0; r < 4; ++r) {
        int q = q0 + w * 64 + mi * 16 + quad * 4 + r;
        ctx[(size_t)(b * 2048 + q) * 1024 + col] = fast_bf16(o[mi][ni][r] * rl[r]);
      }
    }
  }
}

extern "C" void kernel_launch(void* const* d_in, const int* in_sizes, int n_in,
                              void* d_out, int out_size, void* d_ws, size_t ws_size,
                              hipStream_t stream) {
  const float* x  = (const float*)d_in[0];
  const float* Wq = (const float*)d_in[1];
  const float* bq = (const float*)d_in[2];
  const float* Wk = (const float*)d_in[3];
  const float* bk = (const float*)d_in[4];
  const float* Wv = (const float*)d_in[5];
  const float* bv = (const float*)d_in[6];
  const float* Wo = (const float*)d_in[7];
  const float* bo = (const float*)d_in[8];
  float* out = (float*)d_out;

  char* ws = (char*)d_ws;
  const size_t MB = 1048576;
  bf16* xb  = (bf16*)(ws);             // 16 MB: x bf16 [8192][1024]
  bf16* Wt  = (bf16*)(ws + 16 * MB);   //  6 MB: Wqkv^T [3072][1024]
  bf16* Wot = (bf16*)(ws + 22 * MB);   //  2 MB: Wo^T   [1024][1024]
  bf16* Qb  = (bf16*)(ws + 24 * MB);   // 16 MB: Q [64][2048][64] (pre-scaled by log2e/8)
  bf16* Kb  = (bf16*)(ws + 40 * MB);   // 16 MB: K [64][2048][64]
  bf16* Vtb = (bf16*)(ws + 56 * MB);   // 16 MB: V^T [64][64][2048]
  bf16* Cx  = (bf16*)(ws + 72 * MB);   // 16 MB: ctx [8192][1024]

  cast_f32_bf16<<<8192, 256, 0, stream>>>(x, xb, 8388608);
  transpose_weights<<<dim3(16, 16, 4), 256, 0, stream>>>(Wq, Wk, Wv, Wo, Wt, Wot);
  gemm_qkv<<<dim3(24, 32, 1), 512, 0, stream>>>(xb, Wt, bq, bk, bv, Qb, Kb, Vtb);
  attn<<<dim3(64, 8, 1), 256, 0, stream>>>(Qb, Kb, Vtb, Cx);
  gemm_out<<<dim3(8, 32, 1), 512, 0, stream>>>(Cx, Wot, bo, out);
}

// Round 6
// 263.589 us; speedup vs baseline: 1.6895x; 1.6895x over previous
//
#include <hip/hip_runtime.h>
#include <hip/hip_bf16.h>
#include <stdint.h>

typedef __bf16 bf16;
typedef __bf16 bf16x4 __attribute__((ext_vector_type(4)));
typedef __bf16 bf16x8 __attribute__((ext_vector_type(8)));
typedef float f32x4 __attribute__((ext_vector_type(4)));

// async global->LDS, 16B per lane. LDS dest is wave-uniform base + lane*16.
__device__ __forceinline__ void async_ld16(const void* g, void* l) {
  __builtin_amdgcn_global_load_lds(
      (__attribute__((address_space(1))) void*)(void*)(g),
      (__attribute__((address_space(3))) void*)(l), 16, 0, 0);
}

// fast f32->bf16 (round-half-up): 2 VALU ops. Values are finite, non-NaN.
__device__ __forceinline__ bf16 fast_bf16(float f) {
  uint32_t u = (__float_as_uint(f) + 0x8000u) >> 16;
  union { uint16_t s; bf16 b; } cv;
  cv.s = (uint16_t)u;
  return cv.b;
}

// pack two f32 -> bf16x2 in a u32: 2 adds + 1 v_perm_b32. (VERIFIED bit-exact;
// R2's v_cvt_pk_bf16_f32 asm replacement FAILED correctness - do not retry
// without an isolated layout probe.)
__device__ __forceinline__ uint32_t pack_bf16(float lo, float hi) {
  return __builtin_amdgcn_perm(__float_as_uint(hi) + 0x8000u,
                               __float_as_uint(lo) + 0x8000u, 0x07060302u);
}

// ---------------- cast x fp32 -> bf16 ----------------
__global__ __launch_bounds__(256) void cast_f32_bf16(const float* __restrict__ in,
                                                     bf16* __restrict__ out, int n) {
  int i = (blockIdx.x * 256 + threadIdx.x) * 4;
  if (i < n) {
    float4 f = *(const float4*)(in + i);
    uint2 o;
    o.x = pack_bf16(f.x, f.y);
    o.y = pack_bf16(f.z, f.w);
    *(uint2*)(out + i) = o;
  }
}

// ---------------- fused weight transpose-cast: Wq/Wk/Wv -> Wt, Wo -> Wot ----------------
__global__ __launch_bounds__(256) void transpose_weights(const float* __restrict__ Wq,
                                                         const float* __restrict__ Wk,
                                                         const float* __restrict__ Wv,
                                                         const float* __restrict__ Wo,
                                                         bf16* __restrict__ Wt,
                                                         bf16* __restrict__ Wot) {
  __shared__ bf16 tile[64][66];
  int z = blockIdx.z;
  const float* src = z == 0 ? Wq : (z == 1 ? Wk : (z == 2 ? Wv : Wo));
  bf16* dst = z == 0 ? Wt : (z == 1 ? Wt + 1048576 : (z == 2 ? Wt + 2097152 : Wot));
  int r0 = blockIdx.x * 64, c0 = blockIdx.y * 64;
  int t = threadIdx.x;
#pragma unroll
  for (int i = 0; i < 16; ++i) {
    int idx = t + i * 256;
    int r = idx >> 6, c = idx & 63;
    tile[r][c] = fast_bf16(src[(size_t)(r0 + r) * 1024 + (c0 + c)]);
  }
  __syncthreads();
#pragma unroll
  for (int i = 0; i < 16; ++i) {
    int idx = t + i * 256;
    int c = idx >> 6, r = idx & 63;
    dst[(size_t)(c0 + c) * 1024 + (r0 + r)] = tile[r][c];
  }
}

// ---------------- 256x128 pipelined bf16 GEMM mainloop (R4-proven) ----------------
// 8 waves (4M x 2N, per-wave 64x64), K=1024, XOR-swizzled LDS (chunk c of row r
// at position c^(r&7); all fragment reads use rows == l15 mod 8 -> conflict-free).
// Next K-step staged EARLY (phases 0-1) into the dead buffer; ONE barrier per
// K-step (issue-to-drain gap >= 2 fenced phases hides VMEM latency).
// smem layout: buf b at smem + b*24576 (A 256x64 | B 128x64).
__device__ __forceinline__ void gemm256_mainloop(const bf16* __restrict__ A,
                                                 const bf16* __restrict__ Bt,
                                                 int rowBase, int colBase,
                                                 bf16* smem, f32x4 (&acc)[4][4]) {
  int t = threadIdx.x, lane = t & 63, w = t >> 6;          // w 0..7
  int wM = w >> 1, wN = w & 1, quad = lane >> 4, l15 = lane & 15;
  int r_off = lane >> 3;
  int c_sw = (((lane & 7) ^ r_off) << 3);
  int sw = l15 & 7;

  // prologue: stage K-step 0 into buf 0 (A: 4 loads/thread, B: 2)
#pragma unroll
  for (int i = 0; i < 4; ++i) {
    int e = (w * 4 + i) * 512;
    int row = (e >> 6) + r_off;
    async_ld16(A + (size_t)(rowBase + row) * 1024 + c_sw, smem + e);
  }
#pragma unroll
  for (int i = 0; i < 2; ++i) {
    int e = (w * 2 + i) * 512;
    int row = (e >> 6) + r_off;
    async_ld16(Bt + (size_t)(colBase + row) * 1024 + c_sw, smem + 16384 + e);
  }
  __syncthreads();  // drains vmcnt: step 0 resident

  for (int kt = 0; kt < 16; ++kt) {
    int cur = kt & 1;
    const bf16* As = smem + cur * 24576;
    const bf16* Bs = As + 16384;
    bf16* Asn = smem + (cur ^ 1) * 24576;
    bf16* Bsn = Asn + 16384;
    int kn = (kt + 1) * 64;

    bf16x8 af[4], bfr[2];

    // ---- ph0: issue A-stage(kt+1); read A ks0 + B ni{0,1} ks0; 8 MFMA ----
    if (kt < 15) {
#pragma unroll
      for (int i = 0; i < 4; ++i) {
        int e = (w * 4 + i) * 512;
        int row = (e >> 6) + r_off;
        async_ld16(A + (size_t)(rowBase + row) * 1024 + (kn + c_sw), Asn + e);
      }
    }
    {
      int co = ((quad ^ sw) << 3);  // ks = 0
#pragma unroll
      for (int mi = 0; mi < 4; ++mi)
        af[mi] = *(const bf16x8*)(As + (wM * 64 + mi * 16 + l15) * 64 + co);
      bfr[0] = *(const bf16x8*)(Bs + (wN * 64 + l15) * 64 + co);
      bfr[1] = *(const bf16x8*)(Bs + (wN * 64 + 16 + l15) * 64 + co);
      asm volatile("s_waitcnt lgkmcnt(0)" ::: "memory");
      __builtin_amdgcn_sched_barrier(0);
      __builtin_amdgcn_s_setprio(1);
#pragma unroll
      for (int mi = 0; mi < 4; ++mi) {
        acc[mi][0] = __builtin_amdgcn_mfma_f32_16x16x32_bf16(af[mi], bfr[0], acc[mi][0], 0, 0, 0);
        acc[mi][1] = __builtin_amdgcn_mfma_f32_16x16x32_bf16(af[mi], bfr[1], acc[mi][1], 0, 0, 0);
      }
      __builtin_amdgcn_s_setprio(0);
    }

    // ---- ph1: issue B-stage(kt+1); read B ni{2,3} ks0; 8 MFMA ----
    if (kt < 15) {
#pragma unroll
      for (int i = 0; i < 2; ++i) {
        int e = (w * 2 + i) * 512;
        int row = (e >> 6) + r_off;
        async_ld16(Bt + (size_t)(colBase + row) * 1024 + (kn + c_sw), Bsn + e);
      }
    }
    {
      int co = ((quad ^ sw) << 3);
      bfr[0] = *(const bf16x8*)(Bs + (wN * 64 + 32 + l15) * 64 + co);
      bfr[1] = *(const bf16x8*)(Bs + (wN * 64 + 48 + l15) * 64 + co);
      asm volatile("s_waitcnt lgkmcnt(0)" ::: "memory");
      __builtin_amdgcn_sched_barrier(0);
      __builtin_amdgcn_s_setprio(1);
#pragma unroll
      for (int mi = 0; mi < 4; ++mi) {
        acc[mi][2] = __builtin_amdgcn_mfma_f32_16x16x32_bf16(af[mi], bfr[0], acc[mi][2], 0, 0, 0);
        acc[mi][3] = __builtin_amdgcn_mfma_f32_16x16x32_bf16(af[mi], bfr[1], acc[mi][3], 0, 0, 0);
      }
      __builtin_amdgcn_s_setprio(0);
    }

    // ---- ph2: read A ks1 + B ni{0,1} ks1; 8 MFMA ----
    {
      int co = (((4 + quad) ^ sw) << 3);  // ks = 1
#pragma unroll
      for (int mi = 0; mi < 4; ++mi)
        af[mi] = *(const bf16x8*)(As + (wM * 64 + mi * 16 + l15) * 64 + co);
      bfr[0] = *(const bf16x8*)(Bs + (wN * 64 + l15) * 64 + co);
      bfr[1] = *(const bf16x8*)(Bs + (wN * 64 + 16 + l15) * 64 + co);
      asm volatile("s_waitcnt lgkmcnt(0)" ::: "memory");
      __builtin_amdgcn_sched_barrier(0);
      __builtin_amdgcn_s_setprio(1);
#pragma unroll
      for (int mi = 0; mi < 4; ++mi) {
        acc[mi][0] = __builtin_amdgcn_mfma_f32_16x16x32_bf16(af[mi], bfr[0], acc[mi][0], 0, 0, 0);
        acc[mi][1] = __builtin_amdgcn_mfma_f32_16x16x32_bf16(af[mi], bfr[1], acc[mi][1], 0, 0, 0);
      }
      __builtin_amdgcn_s_setprio(0);
    }

    // ---- ph3: read B ni{2,3} ks1; 8 MFMA ----
    {
      int co = (((4 + quad) ^ sw) << 3);
      bfr[0] = *(const bf16x8*)(Bs + (wN * 64 + 32 + l15) * 64 + co);
      bfr[1] = *(const bf16x8*)(Bs + (wN * 64 + 48 + l15) * 64 + co);
      asm volatile("s_waitcnt lgkmcnt(0)" ::: "memory");
      __builtin_amdgcn_sched_barrier(0);
      __builtin_amdgcn_s_setprio(1);
#pragma unroll
      for (int mi = 0; mi < 4; ++mi) {
        acc[mi][2] = __builtin_amdgcn_mfma_f32_16x16x32_bf16(af[mi], bfr[0], acc[mi][2], 0, 0, 0);
        acc[mi][3] = __builtin_amdgcn_mfma_f32_16x16x32_bf16(af[mi], bfr[1], acc[mi][3], 0, 0, 0);
      }
      __builtin_amdgcn_s_setprio(0);
    }

    // end-of-step: all waves done reading buf[cur]; buf[cur^1] stages (issued
    // >= 2 phases ago) drain cheaply in the barrier's implicit vmcnt(0).
    __syncthreads();
  }
}

// GEMM1: X[8192,1024] @ Wqkv^T[3072,1024] -> Q/K [bh][s][d], V^T [bh][d][s].
// R4-proven pipelined mainloop; epilogues through LDS re-tiles for coalesced
// b128 stores. Grid 24x32 = 768 blocks = exactly 3 full-residency rounds.
__global__ __launch_bounds__(512, 2) void gemm_qkv(const bf16* __restrict__ X,
                                                   const bf16* __restrict__ Wt,
                                                   const float* __restrict__ bq,
                                                   const float* __restrict__ bk,
                                                   const float* __restrict__ bv,
                                                   bf16* __restrict__ Qo,
                                                   bf16* __restrict__ Ko,
                                                   bf16* __restrict__ Vto) {
  __shared__ alignas(16) bf16 smem[2 * 24576];  // 96 KB

  int t = threadIdx.x, lane = t & 63, w = t >> 6;
  int wM = w >> 1, wN = w & 1, quad = lane >> 4, l15 = lane & 15;
  int rowBase = blockIdx.y * 256, colBase = blockIdx.x * 128;

  f32x4 acc[4][4];
  f32x4 z = {0.f, 0.f, 0.f, 0.f};
#pragma unroll
  for (int mi = 0; mi < 4; ++mi)
#pragma unroll
    for (int ni = 0; ni < 4; ++ni) acc[mi][ni] = z;

  gemm256_mainloop(X, Wt, rowBase, colBase, smem, acc);

  // ---------------- epilogue (verified patterns, 256-row sizes) ----------------
  int which = colBase >> 10;  // 0:q 1:k 2:v (128-tiles never straddle)
  int baseh = (colBase & 1023) >> 6;
  int b = rowBase >> 11, s0 = rowBase & 2047;
  bf16* ep = smem;

  if (which == 2) {
    // V^T [bh][d][s]: LDS re-tile [64 d][256 s (+8 pad)], coalesced b128 stores.
#pragma unroll
    for (int hp = 0; hp < 2; ++hp) {
      __syncthreads();
      if (wN == hp) {
#pragma unroll
        for (int mi = 0; mi < 4; ++mi)
#pragma unroll
          for (int ni = 0; ni < 4; ++ni) {
            int d = ni * 16 + l15;
            float bb = bv[(colBase & 1023) + hp * 64 + d];
            int sl = wM * 64 + mi * 16 + quad * 4;
            uint2 pv;
            pv.x = pack_bf16(acc[mi][ni][0] + bb, acc[mi][ni][1] + bb);
            pv.y = pack_bf16(acc[mi][ni][2] + bb, acc[mi][ni][3] + bb);
            *(uint2*)(ep + d * 264 + sl) = pv;
          }
      }
      __syncthreads();
      int hg = baseh + hp;
#pragma unroll
      for (int it = 0; it < 4; ++it) {
        int idx = t + it * 512;
        int d = idx >> 5, c = idx & 31;
        bf16x8 vv = *(const bf16x8*)(ep + d * 264 + c * 8);
        *(bf16x8*)(Vto + (((size_t)((b << 4) + hg) << 6) + d) * 2048 + s0 + c * 8) = vv;
      }
    }
  } else {
    // Q/K [bh][s][d]: stage [256 s][64 d] (+pad), contiguous 32 KB global region.
    const float* bias = which == 0 ? bq : bk;
    bf16* dst = which == 0 ? Qo : Ko;
    float scale = which == 0 ? 0.125f * 1.44269504f : 1.0f;
#pragma unroll
    for (int hp = 0; hp < 2; ++hp) {
      __syncthreads();
      if (wN == hp) {
#pragma unroll
        for (int mi = 0; mi < 4; ++mi)
#pragma unroll
          for (int ni = 0; ni < 4; ++ni) {
            int d = ni * 16 + l15;
            float bb = bias[(colBase & 1023) + hp * 64 + d];
            int m = wM * 64 + mi * 16 + quad * 4;
#pragma unroll
            for (int r = 0; r < 4; ++r)
              ep[(m + r) * 72 + d] = fast_bf16((acc[mi][ni][r] + bb) * scale);
          }
      }
      __syncthreads();
      int hg = baseh + hp;
      bf16* gbase = dst + ((((size_t)((b << 4) + hg)) * 2048 + s0) << 6);
#pragma unroll
      for (int it = 0; it < 4; ++it) {
        int idx = t + it * 512;
        int m = idx >> 3, c = idx & 7;
        bf16x8 vv = *(const bf16x8*)(ep + m * 72 + c * 8);
        *(bf16x8*)(gbase + m * 64 + c * 8) = vv;
      }
    }
  }
}

// GEMM2: ctx[8192,1024] @ Wo^T[1024,1024] + bo -> out fp32.
// R5 pipelined 256x128 mainloop; direct fp32 epilogue. Grid 8x32 = 256 blocks.
__global__ __launch_bounds__(512, 2) void gemm_out(const bf16* __restrict__ Cb,
                                                   const bf16* __restrict__ Wot,
                                                   const float* __restrict__ bo,
                                                   float* __restrict__ out) {
  __shared__ alignas(16) bf16 smem[2 * 24576];  // 96 KB

  int t = threadIdx.x, lane = t & 63, w = t >> 6;
  int wM = w >> 1, wN = w & 1, quad = lane >> 4, l15 = lane & 15;
  int rowBase = blockIdx.y * 256, colBase = blockIdx.x * 128;

  f32x4 acc[4][4];
  f32x4 z = {0.f, 0.f, 0.f, 0.f};
#pragma unroll
  for (int mi = 0; mi < 4; ++mi)
#pragma unroll
    for (int ni = 0; ni < 4; ++ni) acc[mi][ni] = z;

  gemm256_mainloop(Cb, Wot, rowBase, colBase, smem, acc);

#pragma unroll
  for (int mi = 0; mi < 4; ++mi)
#pragma unroll
    for (int ni = 0; ni < 4; ++ni) {
      int n = colBase + wN * 64 + ni * 16 + l15;
      float bb = bo[n];
#pragma unroll
      for (int r = 0; r < 4; ++r) {
        int m = rowBase + wM * 64 + mi * 16 + quad * 4 + r;
        out[(size_t)m * 1024 + n] = acc[mi][ni][r] + bb;
      }
    }
}

// ---------------- flash attention: 256q blocks, 64q/wave, half-split pipeline ----
// EXACT R3 kernel (measured 87.7/89.5 us): R4 addressing (conflict-free
// XOR-swizzled P, 64-wide rows) + half-split exp/PV overlap + l via ones-B MFMA
// + T5 setprio. dbuf K/V, (256,2), 104 VGPR.
// CLOSED levers: R1 (32q/wave: dup K-frag LDS reads, +18%), R5 ((256,3):
// VGPR split 84 -> 700MB scratch spill, 3x slower). Do not reopen occupancy.
__global__ __launch_bounds__(256, 2) void attn(const bf16* __restrict__ Q,
                                               const bf16* __restrict__ Kg,
                                               const bf16* __restrict__ Vt,
                                               bf16* __restrict__ ctx) {
  __shared__ alignas(16) bf16 QPs[256 * 64];   // 32 KB: Q stage, then per-wave P
  __shared__ alignas(16) bf16 Ks[2][4096];     // 16 KB [key][dh] swizzled, dbuf
  __shared__ alignas(16) bf16 Vs[2][4096];     // 16 KB [dh][key] swizzled, dbuf

  int t = threadIdx.x, lane = t & 63, w = t >> 6;
  int quad = lane >> 4, l15 = lane & 15;
  int r_off = lane >> 3;
  int c_sw = (((lane & 7) ^ r_off) << 3);
  int sw = l15 & 7;
  int bh = blockIdx.x;
  int q0 = blockIdx.y * 256;
  const bf16* Qp = Q + ((size_t)bh * 2048 + q0) * 64;
  const bf16* Kp = Kg + (size_t)bh * 2048 * 64;
  const bf16* Vp = Vt + (size_t)bh * 64 * 2048;

  // prologue: stage own wave's 64 Q rows + K/V tile 0 into buf 0
#pragma unroll
  for (int i = 0; i < 8; ++i) {
    int e = w * 4096 + i * 512;
    int row = (e >> 6) + r_off;
    async_ld16(Qp + (size_t)row * 64 + c_sw, QPs + e);
  }
#pragma unroll
  for (int i = 0; i < 2; ++i) {
    int e = w * 1024 + i * 512;
    int row = (e >> 6) + r_off;
    async_ld16(Kp + (size_t)row * 64 + c_sw, Ks[0] + e);
    async_ld16(Vp + (size_t)row * 2048 + c_sw, Vs[0] + e);
  }
  __syncthreads();  // drains vmcnt: Q + tile0 ready

  // Q B-fragments: 8 x bf16x8 = 32 VGPRs (own wave's 64 rows)
  bf16x8 qf[2][4];
#pragma unroll
  for (int ks = 0; ks < 2; ++ks)
#pragma unroll
    for (int qi = 0; qi < 4; ++qi)
      qf[ks][qi] = *(const bf16x8*)(QPs + (w * 64 + qi * 16 + l15) * 64 + (((ks * 4 + quad) ^ sw) << 3));
  asm volatile("s_waitcnt lgkmcnt(0)" ::: "memory");  // qf in regs before P overwrites

  bf16* Ps = QPs + w * 4096;  // per-wave 64x64 P buffer == own Q rows (safe overlay)

  bf16 one1 = (bf16)1.0f;
  bf16x8 ones = {one1, one1, one1, one1, one1, one1, one1, one1};

  f32x4 o[4][4];
  f32x4 ol[4];
  f32x4 z = {0.f, 0.f, 0.f, 0.f};
#pragma unroll
  for (int mi = 0; mi < 4; ++mi) {
    ol[mi] = z;
#pragma unroll
    for (int ni = 0; ni < 4; ++ni) o[mi][ni] = z;
  }

  for (int kt = 0; kt < 32; ++kt) {
    int cur = kt & 1;
    // prefetch next K/V tile into the other buffer (overlaps compute below)
    if (kt < 31) {
      int kn = (kt + 1) * 64;
#pragma unroll
      for (int i = 0; i < 2; ++i) {
        int e = w * 1024 + i * 512;
        int row = (e >> 6) + r_off;
        async_ld16(Kp + (size_t)(kn + row) * 64 + c_sw, Ks[cur ^ 1] + e);
        async_ld16(Vp + (size_t)row * 2048 + kn + c_sw, Vs[cur ^ 1] + e);
      }
    }
    const bf16* Kc = Ks[cur];
    const bf16* Vc = Vs[cur];

    // ---- S^T keys 0..31 (ki=0,1) ----
    f32x4 sA[2][4];
#pragma unroll
    for (int ki = 0; ki < 2; ++ki)
#pragma unroll
      for (int qi = 0; qi < 4; ++qi) sA[ki][qi] = z;
    __builtin_amdgcn_s_setprio(1);
#pragma unroll
    for (int ks = 0; ks < 2; ++ks) {
      int co = (((ks * 4 + quad) ^ sw) << 3);
      bf16x8 kf0 = *(const bf16x8*)(Kc + (l15) * 64 + co);
      bf16x8 kf1 = *(const bf16x8*)(Kc + (16 + l15) * 64 + co);
#pragma unroll
      for (int qi = 0; qi < 4; ++qi) {
        sA[0][qi] = __builtin_amdgcn_mfma_f32_16x16x32_bf16(kf0, qf[ks][qi], sA[0][qi], 0, 0, 0);
        sA[1][qi] = __builtin_amdgcn_mfma_f32_16x16x32_bf16(kf1, qf[ks][qi], sA[1][qi], 0, 0, 0);
      }
    }
    __builtin_amdgcn_s_setprio(0);
    // exp + pack + write P half A (logical chunks 0..3, R4 swizzle)
#pragma unroll
    for (int qi = 0; qi < 4; ++qi)
#pragma unroll
      for (int ki = 0; ki < 2; ++ki) {
        float p0 = __builtin_amdgcn_exp2f(sA[ki][qi][0]);
        float p1 = __builtin_amdgcn_exp2f(sA[ki][qi][1]);
        float p2 = __builtin_amdgcn_exp2f(sA[ki][qi][2]);
        float p3 = __builtin_amdgcn_exp2f(sA[ki][qi][3]);
        uint2 pb;
        pb.x = pack_bf16(p0, p1);
        pb.y = pack_bf16(p2, p3);
        int cs = (ki * 2 + (quad >> 1)) ^ sw;
        *(uint2*)(Ps + (qi * 16 + l15) * 64 + cs * 8 + (quad & 1) * 4) = pb;
      }

    // ---- S^T keys 32..63 (ki=2,3) ----
    f32x4 sB[2][4];
#pragma unroll
    for (int ki = 0; ki < 2; ++ki)
#pragma unroll
      for (int qi = 0; qi < 4; ++qi) sB[ki][qi] = z;
    __builtin_amdgcn_s_setprio(1);
#pragma unroll
    for (int ks = 0; ks < 2; ++ks) {
      int co = (((ks * 4 + quad) ^ sw) << 3);
      bf16x8 kf2 = *(const bf16x8*)(Kc + (32 + l15) * 64 + co);
      bf16x8 kf3 = *(const bf16x8*)(Kc + (48 + l15) * 64 + co);
#pragma unroll
      for (int qi = 0; qi < 4; ++qi) {
        sB[0][qi] = __builtin_amdgcn_mfma_f32_16x16x32_bf16(kf2, qf[ks][qi], sB[0][qi], 0, 0, 0);
        sB[1][qi] = __builtin_amdgcn_mfma_f32_16x16x32_bf16(kf3, qf[ks][qi], sB[1][qi], 0, 0, 0);
      }
    }
    __builtin_amdgcn_s_setprio(0);

    asm volatile("s_waitcnt lgkmcnt(0)" ::: "memory");  // P half A visible

    // ---- PV half A (keys 0..31, ks=0) + l row-sum ----
    {
      int co = ((quad ^ sw) << 3);
      bf16x8 pf[4], vf[4];
#pragma unroll
      for (int mi = 0; mi < 4; ++mi)
        pf[mi] = *(const bf16x8*)(Ps + (mi * 16 + l15) * 64 + co);
#pragma unroll
      for (int ni = 0; ni < 4; ++ni)
        vf[ni] = *(const bf16x8*)(Vc + (ni * 16 + l15) * 64 + co);
      __builtin_amdgcn_s_setprio(1);
#pragma unroll
      for (int mi = 0; mi < 4; ++mi) {
#pragma unroll
        for (int ni = 0; ni < 4; ++ni)
          o[mi][ni] = __builtin_amdgcn_mfma_f32_16x16x32_bf16(pf[mi], vf[ni], o[mi][ni], 0, 0, 0);
        ol[mi] = __builtin_amdgcn_mfma_f32_16x16x32_bf16(pf[mi], ones, ol[mi], 0, 0, 0);
      }
      __builtin_amdgcn_s_setprio(0);
    }

    // exp + pack + write P half B (logical chunks 4..7) — overlaps PV-A MFMAs
#pragma unroll
    for (int qi = 0; qi < 4; ++qi)
#pragma unroll
      for (int ki = 0; ki < 2; ++ki) {
        float p0 = __builtin_amdgcn_exp2f(sB[ki][qi][0]);
        float p1 = __builtin_amdgcn_exp2f(sB[ki][qi][1]);
        float p2 = __builtin_amdgcn_exp2f(sB[ki][qi][2]);
        float p3 = __builtin_amdgcn_exp2f(sB[ki][qi][3]);
        uint2 pb;
        pb.x = pack_bf16(p0, p1);
        pb.y = pack_bf16(p2, p3);
        int cs = (ki * 2 + 4 + (quad >> 1)) ^ sw;
        *(uint2*)(Ps + (qi * 16 + l15) * 64 + cs * 8 + (quad & 1) * 4) = pb;
      }

    asm volatile("s_waitcnt lgkmcnt(0)" ::: "memory");  // P half B visible

    // ---- PV half B (keys 32..63, ks=1) + l row-sum ----
    {
      int co = (((4 + quad) ^ sw) << 3);
      bf16x8 pf[4], vf[4];
#pragma unroll
      for (int mi = 0; mi < 4; ++mi)
        pf[mi] = *(const bf16x8*)(Ps + (mi * 16 + l15) * 64 + co);
#pragma unroll
      for (int ni = 0; ni < 4; ++ni)
        vf[ni] = *(const bf16x8*)(Vc + (ni * 16 + l15) * 64 + co);
      __builtin_amdgcn_s_setprio(1);
#pragma unroll
      for (int mi = 0; mi < 4; ++mi) {
#pragma unroll
        for (int ni = 0; ni < 4; ++ni)
          o[mi][ni] = __builtin_amdgcn_mfma_f32_16x16x32_bf16(pf[mi], vf[ni], o[mi][ni], 0, 0, 0);
        ol[mi] = __builtin_amdgcn_mfma_f32_16x16x32_bf16(pf[mi], ones, ol[mi], 0, 0, 0);
      }
      __builtin_amdgcn_s_setprio(0);
    }

    // end-of-tile barrier: all waves done with buf[cur]; vmcnt(0) drain lands
    // after a full compute phase -> prefetch latency hidden.
    __syncthreads();
  }

  // epilogue: ol[mi][r] = l for query mi*16+quad*4+r (uniform across l15)
  int b = bh >> 4, h = bh & 15;
#pragma unroll
  for (int mi = 0; mi < 4; ++mi) {
    float rl[4];
#pragma unroll
    for (int r = 0; r < 4; ++r) rl[r] = 1.0f / ol[mi][r];
#pragma unroll
    for (int ni = 0; ni < 4; ++ni) {
      int col = h * 64 + ni * 16 + l15;
#pragma unroll
      for (int r = 0; r < 4; ++r) {
        int q = q0 + w * 64 + mi * 16 + quad * 4 + r;
        ctx[(size_t)(b * 2048 + q) * 1024 + col] = fast_bf16(o[mi][ni][r] * rl[r]);
      }
    }
  }
}

extern "C" void kernel_launch(void* const* d_in, const int* in_sizes, int n_in,
                              void* d_out, int out_size, void* d_ws, size_t ws_size,
                              hipStream_t stream) {
  const float* x  = (const float*)d_in[0];
  const float* Wq = (const float*)d_in[1];
  const float* bq = (const float*)d_in[2];
  const float* Wk = (const float*)d_in[3];
  const float* bk = (const float*)d_in[4];
  const float* Wv = (const float*)d_in[5];
  const float* bv = (const float*)d_in[6];
  const float* Wo = (const float*)d_in[7];
  const float* bo = (const float*)d_in[8];
  float* out = (float*)d_out;

  char* ws = (char*)d_ws;
  const size_t MB = 1048576;
  bf16* xb  = (bf16*)(ws);             // 16 MB: x bf16 [8192][1024]
  bf16* Wt  = (bf16*)(ws + 16 * MB);   //  6 MB: Wqkv^T [3072][1024]
  bf16* Wot = (bf16*)(ws + 22 * MB);   //  2 MB: Wo^T   [1024][1024]
  bf16* Qb  = (bf16*)(ws + 24 * MB);   // 16 MB: Q [64][2048][64] (pre-scaled by log2e/8)
  bf16* Kb  = (bf16*)(ws + 40 * MB);   // 16 MB: K [64][2048][64]
  bf16* Vtb = (bf16*)(ws + 56 * MB);   // 16 MB: V^T [64][64][2048]
  bf16* Cx  = (bf16*)(ws + 72 * MB);   // 16 MB: ctx [8192][1024]

  cast_f32_bf16<<<8192, 256, 0, stream>>>(x, xb, 8388608);
  transpose_weights<<<dim3(16, 16, 4), 256, 0, stream>>>(Wq, Wk, Wv, Wo, Wt, Wot);
  gemm_qkv<<<dim3(24, 32, 1), 512, 0, stream>>>(xb, Wt, bq, bk, bv, Qb, Kb, Vtb);
  attn<<<dim3(64, 8, 1), 256, 0, stream>>>(Qb, Kb, Vtb, Cx);
  gemm_out<<<dim3(8, 32, 1), 512, 0, stream>>>(Cx, Wot, bo, out);
}

// Round 7
// 256.206 us; speedup vs baseline: 1.7382x; 1.0288x over previous
//
#include <hip/hip_runtime.h>
#include <hip/hip_bf16.h>
#include <stdint.h>

typedef __bf16 bf16;
typedef __bf16 bf16x4 __attribute__((ext_vector_type(4)));
typedef __bf16 bf16x8 __attribute__((ext_vector_type(8)));
typedef float f32x4 __attribute__((ext_vector_type(4)));

// async global->LDS, 16B per lane. LDS dest is wave-uniform base + lane*16.
__device__ __forceinline__ void async_ld16(const void* g, void* l) {
  __builtin_amdgcn_global_load_lds(
      (__attribute__((address_space(1))) void*)(void*)(g),
      (__attribute__((address_space(3))) void*)(l), 16, 0, 0);
}

// fast f32->bf16 (round-half-up): 2 VALU ops. Values are finite, non-NaN.
__device__ __forceinline__ bf16 fast_bf16(float f) {
  uint32_t u = (__float_as_uint(f) + 0x8000u) >> 16;
  union { uint16_t s; bf16 b; } cv;
  cv.s = (uint16_t)u;
  return cv.b;
}

// pack two f32 -> bf16x2 in a u32: 2 adds + 1 v_perm_b32. (VERIFIED bit-exact;
// R2's v_cvt_pk_bf16_f32 asm replacement FAILED correctness - do not retry
// without an isolated layout probe.)
__device__ __forceinline__ uint32_t pack_bf16(float lo, float hi) {
  return __builtin_amdgcn_perm(__float_as_uint(hi) + 0x8000u,
                               __float_as_uint(lo) + 0x8000u, 0x07060302u);
}

// ---------------- fused prep: cast x fp32->bf16  +  weight transpose-cast ----
// blocks [0, 8192): cast 1024 f32 each. blocks [8192, 9216): transpose tiles.
// One launch instead of two (saves a serial launch gap in the graph).
__global__ __launch_bounds__(256) void prep(const float* __restrict__ x,
                                            bf16* __restrict__ xb,
                                            const float* __restrict__ Wq,
                                            const float* __restrict__ Wk,
                                            const float* __restrict__ Wv,
                                            const float* __restrict__ Wo,
                                            bf16* __restrict__ Wt,
                                            bf16* __restrict__ Wot) {
  __shared__ bf16 tile[64][66];
  int t = threadIdx.x;
  if (blockIdx.x < 8192) {
    int i = (blockIdx.x * 256 + t) * 4;
    float4 f = *(const float4*)(x + i);
    uint2 o;
    o.x = pack_bf16(f.x, f.y);
    o.y = pack_bf16(f.z, f.w);
    *(uint2*)(xb + i) = o;
  } else {
    int tb = blockIdx.x - 8192;
    int z = tb >> 8;
    int tb2 = tb & 255;
    const float* src = z == 0 ? Wq : (z == 1 ? Wk : (z == 2 ? Wv : Wo));
    bf16* dst = z == 0 ? Wt : (z == 1 ? Wt + 1048576 : (z == 2 ? Wt + 2097152 : Wot));
    int r0 = (tb2 & 15) * 64, c0 = (tb2 >> 4) * 64;
#pragma unroll
    for (int i = 0; i < 16; ++i) {
      int idx = t + i * 256;
      int r = idx >> 6, c = idx & 63;
      tile[r][c] = fast_bf16(src[(size_t)(r0 + r) * 1024 + (c0 + c)]);
    }
    __syncthreads();
#pragma unroll
    for (int i = 0; i < 16; ++i) {
      int idx = t + i * 256;
      int c = idx >> 6, r = idx & 63;
      dst[(size_t)(c0 + c) * 1024 + (r0 + r)] = tile[r][c];
    }
  }
}

// ---------------- 256x128 pipelined bf16 GEMM mainloop (R4-proven) ----------------
// 8 waves (4M x 2N, per-wave 64x64), K=1024, XOR-swizzled LDS (chunk c of row r
// at position c^(r&7); all fragment reads use rows == l15 mod 8 -> conflict-free).
// Next K-step staged EARLY (phases 0-1) into the dead buffer; ONE barrier per
// K-step (issue-to-drain gap >= 2 fenced phases hides VMEM latency).
// smem layout: buf b at smem + b*24576 (A 256x64 | B 128x64).
__device__ __forceinline__ void gemm256_mainloop(const bf16* __restrict__ A,
                                                 const bf16* __restrict__ Bt,
                                                 int rowBase, int colBase,
                                                 bf16* smem, f32x4 (&acc)[4][4]) {
  int t = threadIdx.x, lane = t & 63, w = t >> 6;          // w 0..7
  int wM = w >> 1, wN = w & 1, quad = lane >> 4, l15 = lane & 15;
  int r_off = lane >> 3;
  int c_sw = (((lane & 7) ^ r_off) << 3);
  int sw = l15 & 7;

  // prologue: stage K-step 0 into buf 0 (A: 4 loads/thread, B: 2)
#pragma unroll
  for (int i = 0; i < 4; ++i) {
    int e = (w * 4 + i) * 512;
    int row = (e >> 6) + r_off;
    async_ld16(A + (size_t)(rowBase + row) * 1024 + c_sw, smem + e);
  }
#pragma unroll
  for (int i = 0; i < 2; ++i) {
    int e = (w * 2 + i) * 512;
    int row = (e >> 6) + r_off;
    async_ld16(Bt + (size_t)(colBase + row) * 1024 + c_sw, smem + 16384 + e);
  }
  __syncthreads();  // drains vmcnt: step 0 resident

  for (int kt = 0; kt < 16; ++kt) {
    int cur = kt & 1;
    const bf16* As = smem + cur * 24576;
    const bf16* Bs = As + 16384;
    bf16* Asn = smem + (cur ^ 1) * 24576;
    bf16* Bsn = Asn + 16384;
    int kn = (kt + 1) * 64;

    bf16x8 af[4], bfr[2];

    // ---- ph0: issue A-stage(kt+1); read A ks0 + B ni{0,1} ks0; 8 MFMA ----
    if (kt < 15) {
#pragma unroll
      for (int i = 0; i < 4; ++i) {
        int e = (w * 4 + i) * 512;
        int row = (e >> 6) + r_off;
        async_ld16(A + (size_t)(rowBase + row) * 1024 + (kn + c_sw), Asn + e);
      }
    }
    {
      int co = ((quad ^ sw) << 3);  // ks = 0
#pragma unroll
      for (int mi = 0; mi < 4; ++mi)
        af[mi] = *(const bf16x8*)(As + (wM * 64 + mi * 16 + l15) * 64 + co);
      bfr[0] = *(const bf16x8*)(Bs + (wN * 64 + l15) * 64 + co);
      bfr[1] = *(const bf16x8*)(Bs + (wN * 64 + 16 + l15) * 64 + co);
      asm volatile("s_waitcnt lgkmcnt(0)" ::: "memory");
      __builtin_amdgcn_sched_barrier(0);
      __builtin_amdgcn_s_setprio(1);
#pragma unroll
      for (int mi = 0; mi < 4; ++mi) {
        acc[mi][0] = __builtin_amdgcn_mfma_f32_16x16x32_bf16(af[mi], bfr[0], acc[mi][0], 0, 0, 0);
        acc[mi][1] = __builtin_amdgcn_mfma_f32_16x16x32_bf16(af[mi], bfr[1], acc[mi][1], 0, 0, 0);
      }
      __builtin_amdgcn_s_setprio(0);
    }

    // ---- ph1: issue B-stage(kt+1); read B ni{2,3} ks0; 8 MFMA ----
    if (kt < 15) {
#pragma unroll
      for (int i = 0; i < 2; ++i) {
        int e = (w * 2 + i) * 512;
        int row = (e >> 6) + r_off;
        async_ld16(Bt + (size_t)(colBase + row) * 1024 + (kn + c_sw), Bsn + e);
      }
    }
    {
      int co = ((quad ^ sw) << 3);
      bfr[0] = *(const bf16x8*)(Bs + (wN * 64 + 32 + l15) * 64 + co);
      bfr[1] = *(const bf16x8*)(Bs + (wN * 64 + 48 + l15) * 64 + co);
      asm volatile("s_waitcnt lgkmcnt(0)" ::: "memory");
      __builtin_amdgcn_sched_barrier(0);
      __builtin_amdgcn_s_setprio(1);
#pragma unroll
      for (int mi = 0; mi < 4; ++mi) {
        acc[mi][2] = __builtin_amdgcn_mfma_f32_16x16x32_bf16(af[mi], bfr[0], acc[mi][2], 0, 0, 0);
        acc[mi][3] = __builtin_amdgcn_mfma_f32_16x16x32_bf16(af[mi], bfr[1], acc[mi][3], 0, 0, 0);
      }
      __builtin_amdgcn_s_setprio(0);
    }

    // ---- ph2: read A ks1 + B ni{0,1} ks1; 8 MFMA ----
    {
      int co = (((4 + quad) ^ sw) << 3);  // ks = 1
#pragma unroll
      for (int mi = 0; mi < 4; ++mi)
        af[mi] = *(const bf16x8*)(As + (wM * 64 + mi * 16 + l15) * 64 + co);
      bfr[0] = *(const bf16x8*)(Bs + (wN * 64 + l15) * 64 + co);
      bfr[1] = *(const bf16x8*)(Bs + (wN * 64 + 16 + l15) * 64 + co);
      asm volatile("s_waitcnt lgkmcnt(0)" ::: "memory");
      __builtin_amdgcn_sched_barrier(0);
      __builtin_amdgcn_s_setprio(1);
#pragma unroll
      for (int mi = 0; mi < 4; ++mi) {
        acc[mi][0] = __builtin_amdgcn_mfma_f32_16x16x32_bf16(af[mi], bfr[0], acc[mi][0], 0, 0, 0);
        acc[mi][1] = __builtin_amdgcn_mfma_f32_16x16x32_bf16(af[mi], bfr[1], acc[mi][1], 0, 0, 0);
      }
      __builtin_amdgcn_s_setprio(0);
    }

    // ---- ph3: read B ni{2,3} ks1; 8 MFMA ----
    {
      int co = (((4 + quad) ^ sw) << 3);
      bfr[0] = *(const bf16x8*)(Bs + (wN * 64 + 32 + l15) * 64 + co);
      bfr[1] = *(const bf16x8*)(Bs + (wN * 64 + 48 + l15) * 64 + co);
      asm volatile("s_waitcnt lgkmcnt(0)" ::: "memory");
      __builtin_amdgcn_sched_barrier(0);
      __builtin_amdgcn_s_setprio(1);
#pragma unroll
      for (int mi = 0; mi < 4; ++mi) {
        acc[mi][2] = __builtin_amdgcn_mfma_f32_16x16x32_bf16(af[mi], bfr[0], acc[mi][2], 0, 0, 0);
        acc[mi][3] = __builtin_amdgcn_mfma_f32_16x16x32_bf16(af[mi], bfr[1], acc[mi][3], 0, 0, 0);
      }
      __builtin_amdgcn_s_setprio(0);
    }

    // end-of-step: all waves done reading buf[cur]; buf[cur^1] stages (issued
    // >= 2 phases ago) drain cheaply in the barrier's implicit vmcnt(0).
    __syncthreads();
  }
}

// GEMM1: X[8192,1024] @ Wqkv^T[3072,1024] -> Q/K [bh][s][d], V^T [bh][d][s].
// R4-proven pipelined mainloop. R7: 1-D grid 768 + bijective XCD swizzle
// (768 = 8 XCDs x 96): each XCD walks all 24 col-panels of a row-panel
// sequentially -> A-panel fetched once per XCD (was 8x across XCD L2s).
__global__ __launch_bounds__(512, 2) void gemm_qkv(const bf16* __restrict__ X,
                                                   const bf16* __restrict__ Wt,
                                                   const float* __restrict__ bq,
                                                   const float* __restrict__ bk,
                                                   const float* __restrict__ bv,
                                                   bf16* __restrict__ Qo,
                                                   bf16* __restrict__ Ko,
                                                   bf16* __restrict__ Vto) {
  __shared__ alignas(16) bf16 smem[2 * 24576];  // 96 KB

  int t = threadIdx.x, lane = t & 63, w = t >> 6;
  int wM = w >> 1, wN = w & 1, quad = lane >> 4, l15 = lane & 15;
  int id = blockIdx.x;
  int swz = (id & 7) * 96 + (id >> 3);       // bijective: 768 = 8*96
  int rowBase = (swz / 24) * 256, colBase = (swz % 24) * 128;

  f32x4 acc[4][4];
  f32x4 z = {0.f, 0.f, 0.f, 0.f};
#pragma unroll
  for (int mi = 0; mi < 4; ++mi)
#pragma unroll
    for (int ni = 0; ni < 4; ++ni) acc[mi][ni] = z;

  gemm256_mainloop(X, Wt, rowBase, colBase, smem, acc);

  // ---------------- epilogue (verified patterns, 256-row sizes) ----------------
  int which = colBase >> 10;  // 0:q 1:k 2:v (128-tiles never straddle)
  int baseh = (colBase & 1023) >> 6;
  int b = rowBase >> 11, s0 = rowBase & 2047;
  bf16* ep = smem;

  if (which == 2) {
    // V^T [bh][d][s]: LDS re-tile [64 d][256 s (+8 pad)], coalesced b128 stores.
#pragma unroll
    for (int hp = 0; hp < 2; ++hp) {
      __syncthreads();
      if (wN == hp) {
#pragma unroll
        for (int mi = 0; mi < 4; ++mi)
#pragma unroll
          for (int ni = 0; ni < 4; ++ni) {
            int d = ni * 16 + l15;
            float bb = bv[(colBase & 1023) + hp * 64 + d];
            int sl = wM * 64 + mi * 16 + quad * 4;
            uint2 pv;
            pv.x = pack_bf16(acc[mi][ni][0] + bb, acc[mi][ni][1] + bb);
            pv.y = pack_bf16(acc[mi][ni][2] + bb, acc[mi][ni][3] + bb);
            *(uint2*)(ep + d * 264 + sl) = pv;
          }
      }
      __syncthreads();
      int hg = baseh + hp;
#pragma unroll
      for (int it = 0; it < 4; ++it) {
        int idx = t + it * 512;
        int d = idx >> 5, c = idx & 31;
        bf16x8 vv = *(const bf16x8*)(ep + d * 264 + c * 8);
        *(bf16x8*)(Vto + (((size_t)((b << 4) + hg) << 6) + d) * 2048 + s0 + c * 8) = vv;
      }
    }
  } else {
    // Q/K [bh][s][d]: stage [256 s][64 d] (+pad), contiguous 32 KB global region.
    const float* bias = which == 0 ? bq : bk;
    bf16* dst = which == 0 ? Qo : Ko;
    float scale = which == 0 ? 0.125f * 1.44269504f : 1.0f;
#pragma unroll
    for (int hp = 0; hp < 2; ++hp) {
      __syncthreads();
      if (wN == hp) {
#pragma unroll
        for (int mi = 0; mi < 4; ++mi)
#pragma unroll
          for (int ni = 0; ni < 4; ++ni) {
            int d = ni * 16 + l15;
            float bb = bias[(colBase & 1023) + hp * 64 + d];
            int m = wM * 64 + mi * 16 + quad * 4;
#pragma unroll
            for (int r = 0; r < 4; ++r)
              ep[(m + r) * 72 + d] = fast_bf16((acc[mi][ni][r] + bb) * scale);
          }
      }
      __syncthreads();
      int hg = baseh + hp;
      bf16* gbase = dst + ((((size_t)((b << 4) + hg)) * 2048 + s0) << 6);
#pragma unroll
      for (int it = 0; it < 4; ++it) {
        int idx = t + it * 512;
        int m = idx >> 3, c = idx & 7;
        bf16x8 vv = *(const bf16x8*)(ep + m * 72 + c * 8);
        *(bf16x8*)(gbase + m * 64 + c * 8) = vv;
      }
    }
  }
}

// GEMM2: ctx[8192,1024] @ Wo^T[1024,1024] + bo -> out fp32.
// Pipelined 256x128 mainloop; direct fp32 epilogue. R7: XCD swizzle (256=8*32).
__global__ __launch_bounds__(512, 2) void gemm_out(const bf16* __restrict__ Cb,
                                                   const bf16* __restrict__ Wot,
                                                   const float* __restrict__ bo,
                                                   float* __restrict__ out) {
  __shared__ alignas(16) bf16 smem[2 * 24576];  // 96 KB

  int t = threadIdx.x, lane = t & 63, w = t >> 6;
  int wM = w >> 1, wN = w & 1, quad = lane >> 4, l15 = lane & 15;
  int id = blockIdx.x;
  int swz = (id & 7) * 32 + (id >> 3);       // bijective: 256 = 8*32
  int rowBase = (swz >> 3) * 256, colBase = (swz & 7) * 128;

  f32x4 acc[4][4];
  f32x4 z = {0.f, 0.f, 0.f, 0.f};
#pragma unroll
  for (int mi = 0; mi < 4; ++mi)
#pragma unroll
    for (int ni = 0; ni < 4; ++ni) acc[mi][ni] = z;

  gemm256_mainloop(Cb, Wot, rowBase, colBase, smem, acc);

#pragma unroll
  for (int mi = 0; mi < 4; ++mi)
#pragma unroll
    for (int ni = 0; ni < 4; ++ni) {
      int n = colBase + wN * 64 + ni * 16 + l15;
      float bb = bo[n];
#pragma unroll
      for (int r = 0; r < 4; ++r) {
        int m = rowBase + wM * 64 + mi * 16 + quad * 4 + r;
        out[(size_t)m * 1024 + n] = acc[mi][ni][r] + bb;
      }
    }
}

// ---------------- flash attention: 256q blocks, 64q/wave, half-split pipeline ----
// EXACT R3 kernel (measured 87.7/89.5/89.2 us): R4 addressing (conflict-free
// XOR-swizzled P, 64-wide rows) + half-split exp/PV overlap + l via ones-B MFMA
// + T5 setprio. dbuf K/V, (256,2), 104 VGPR. ~865 TF = plain-HIP 8-warp attn
// endpoint per the catalog; occupancy levers CLOSED (R1: dup K-frag reads +18%;
// R5: forced 3-wave bound -> 84-VGPR split -> 700MB scratch spill, 3x slower).
__global__ __launch_bounds__(256, 2) void attn(const bf16* __restrict__ Q,
                                               const bf16* __restrict__ Kg,
                                               const bf16* __restrict__ Vt,
                                               bf16* __restrict__ ctx) {
  __shared__ alignas(16) bf16 QPs[256 * 64];   // 32 KB: Q stage, then per-wave P
  __shared__ alignas(16) bf16 Ks[2][4096];     // 16 KB [key][dh] swizzled, dbuf
  __shared__ alignas(16) bf16 Vs[2][4096];     // 16 KB [dh][key] swizzled, dbuf

  int t = threadIdx.x, lane = t & 63, w = t >> 6;
  int quad = lane >> 4, l15 = lane & 15;
  int r_off = lane >> 3;
  int c_sw = (((lane & 7) ^ r_off) << 3);
  int sw = l15 & 7;
  int bh = blockIdx.x;
  int q0 = blockIdx.y * 256;
  const bf16* Qp = Q + ((size_t)bh * 2048 + q0) * 64;
  const bf16* Kp = Kg + (size_t)bh * 2048 * 64;
  const bf16* Vp = Vt + (size_t)bh * 64 * 2048;

  // prologue: stage own wave's 64 Q rows + K/V tile 0 into buf 0
#pragma unroll
  for (int i = 0; i < 8; ++i) {
    int e = w * 4096 + i * 512;
    int row = (e >> 6) + r_off;
    async_ld16(Qp + (size_t)row * 64 + c_sw, QPs + e);
  }
#pragma unroll
  for (int i = 0; i < 2; ++i) {
    int e = w * 1024 + i * 512;
    int row = (e >> 6) + r_off;
    async_ld16(Kp + (size_t)row * 64 + c_sw, Ks[0] + e);
    async_ld16(Vp + (size_t)row * 2048 + c_sw, Vs[0] + e);
  }
  __syncthreads();  // drains vmcnt: Q + tile0 ready

  // Q B-fragments: 8 x bf16x8 = 32 VGPRs (own wave's 64 rows)
  bf16x8 qf[2][4];
#pragma unroll
  for (int ks = 0; ks < 2; ++ks)
#pragma unroll
    for (int qi = 0; qi < 4; ++qi)
      qf[ks][qi] = *(const bf16x8*)(QPs + (w * 64 + qi * 16 + l15) * 64 + (((ks * 4 + quad) ^ sw) << 3));
  asm volatile("s_waitcnt lgkmcnt(0)" ::: "memory");  // qf in regs before P overwrites

  bf16* Ps = QPs + w * 4096;  // per-wave 64x64 P buffer == own Q rows (safe overlay)

  bf16 one1 = (bf16)1.0f;
  bf16x8 ones = {one1, one1, one1, one1, one1, one1, one1, one1};

  f32x4 o[4][4];
  f32x4 ol[4];
  f32x4 z = {0.f, 0.f, 0.f, 0.f};
#pragma unroll
  for (int mi = 0; mi < 4; ++mi) {
    ol[mi] = z;
#pragma unroll
    for (int ni = 0; ni < 4; ++ni) o[mi][ni] = z;
  }

  for (int kt = 0; kt < 32; ++kt) {
    int cur = kt & 1;
    // prefetch next K/V tile into the other buffer (overlaps compute below)
    if (kt < 31) {
      int kn = (kt + 1) * 64;
#pragma unroll
      for (int i = 0; i < 2; ++i) {
        int e = w * 1024 + i * 512;
        int row = (e >> 6) + r_off;
        async_ld16(Kp + (size_t)(kn + row) * 64 + c_sw, Ks[cur ^ 1] + e);
        async_ld16(Vp + (size_t)row * 2048 + kn + c_sw, Vs[cur ^ 1] + e);
      }
    }
    const bf16* Kc = Ks[cur];
    const bf16* Vc = Vs[cur];

    // ---- S^T keys 0..31 (ki=0,1) ----
    f32x4 sA[2][4];
#pragma unroll
    for (int ki = 0; ki < 2; ++ki)
#pragma unroll
      for (int qi = 0; qi < 4; ++qi) sA[ki][qi] = z;
    __builtin_amdgcn_s_setprio(1);
#pragma unroll
    for (int ks = 0; ks < 2; ++ks) {
      int co = (((ks * 4 + quad) ^ sw) << 3);
      bf16x8 kf0 = *(const bf16x8*)(Kc + (l15) * 64 + co);
      bf16x8 kf1 = *(const bf16x8*)(Kc + (16 + l15) * 64 + co);
#pragma unroll
      for (int qi = 0; qi < 4; ++qi) {
        sA[0][qi] = __builtin_amdgcn_mfma_f32_16x16x32_bf16(kf0, qf[ks][qi], sA[0][qi], 0, 0, 0);
        sA[1][qi] = __builtin_amdgcn_mfma_f32_16x16x32_bf16(kf1, qf[ks][qi], sA[1][qi], 0, 0, 0);
      }
    }
    __builtin_amdgcn_s_setprio(0);
    // exp + pack + write P half A (logical chunks 0..3, R4 swizzle)
#pragma unroll
    for (int qi = 0; qi < 4; ++qi)
#pragma unroll
      for (int ki = 0; ki < 2; ++ki) {
        float p0 = __builtin_amdgcn_exp2f(sA[ki][qi][0]);
        float p1 = __builtin_amdgcn_exp2f(sA[ki][qi][1]);
        float p2 = __builtin_amdgcn_exp2f(sA[ki][qi][2]);
        float p3 = __builtin_amdgcn_exp2f(sA[ki][qi][3]);
        uint2 pb;
        pb.x = pack_bf16(p0, p1);
        pb.y = pack_bf16(p2, p3);
        int cs = (ki * 2 + (quad >> 1)) ^ sw;
        *(uint2*)(Ps + (qi * 16 + l15) * 64 + cs * 8 + (quad & 1) * 4) = pb;
      }

    // ---- S^T keys 32..63 (ki=2,3) ----
    f32x4 sB[2][4];
#pragma unroll
    for (int ki = 0; ki < 2; ++ki)
#pragma unroll
      for (int qi = 0; qi < 4; ++qi) sB[ki][qi] = z;
    __builtin_amdgcn_s_setprio(1);
#pragma unroll
    for (int ks = 0; ks < 2; ++ks) {
      int co = (((ks * 4 + quad) ^ sw) << 3);
      bf16x8 kf2 = *(const bf16x8*)(Kc + (32 + l15) * 64 + co);
      bf16x8 kf3 = *(const bf16x8*)(Kc + (48 + l15) * 64 + co);
#pragma unroll
      for (int qi = 0; qi < 4; ++qi) {
        sB[0][qi] = __builtin_amdgcn_mfma_f32_16x16x32_bf16(kf2, qf[ks][qi], sB[0][qi], 0, 0, 0);
        sB[1][qi] = __builtin_amdgcn_mfma_f32_16x16x32_bf16(kf3, qf[ks][qi], sB[1][qi], 0, 0, 0);
      }
    }
    __builtin_amdgcn_s_setprio(0);

    asm volatile("s_waitcnt lgkmcnt(0)" ::: "memory");  // P half A visible

    // ---- PV half A (keys 0..31, ks=0) + l row-sum ----
    {
      int co = ((quad ^ sw) << 3);
      bf16x8 pf[4], vf[4];
#pragma unroll
      for (int mi = 0; mi < 4; ++mi)
        pf[mi] = *(const bf16x8*)(Ps + (mi * 16 + l15) * 64 + co);
#pragma unroll
      for (int ni = 0; ni < 4; ++ni)
        vf[ni] = *(const bf16x8*)(Vc + (ni * 16 + l15) * 64 + co);
      __builtin_amdgcn_s_setprio(1);
#pragma unroll
      for (int mi = 0; mi < 4; ++mi) {
#pragma unroll
        for (int ni = 0; ni < 4; ++ni)
          o[mi][ni] = __builtin_amdgcn_mfma_f32_16x16x32_bf16(pf[mi], vf[ni], o[mi][ni], 0, 0, 0);
        ol[mi] = __builtin_amdgcn_mfma_f32_16x16x32_bf16(pf[mi], ones, ol[mi], 0, 0, 0);
      }
      __builtin_amdgcn_s_setprio(0);
    }

    // exp + pack + write P half B (logical chunks 4..7) — overlaps PV-A MFMAs
#pragma unroll
    for (int qi = 0; qi < 4; ++qi)
#pragma unroll
      for (int ki = 0; ki < 2; ++ki) {
        float p0 = __builtin_amdgcn_exp2f(sB[ki][qi][0]);
        float p1 = __builtin_amdgcn_exp2f(sB[ki][qi][1]);
        float p2 = __builtin_amdgcn_exp2f(sB[ki][qi][2]);
        float p3 = __builtin_amdgcn_exp2f(sB[ki][qi][3]);
        uint2 pb;
        pb.x = pack_bf16(p0, p1);
        pb.y = pack_bf16(p2, p3);
        int cs = (ki * 2 + 4 + (quad >> 1)) ^ sw;
        *(uint2*)(Ps + (qi * 16 + l15) * 64 + cs * 8 + (quad & 1) * 4) = pb;
      }

    asm volatile("s_waitcnt lgkmcnt(0)" ::: "memory");  // P half B visible

    // ---- PV half B (keys 32..63, ks=1) + l row-sum ----
    {
      int co = (((4 + quad) ^ sw) << 3);
      bf16x8 pf[4], vf[4];
#pragma unroll
      for (int mi = 0; mi < 4; ++mi)
        pf[mi] = *(const bf16x8*)(Ps + (mi * 16 + l15) * 64 + co);
#pragma unroll
      for (int ni = 0; ni < 4; ++ni)
        vf[ni] = *(const bf16x8*)(Vc + (ni * 16 + l15) * 64 + co);
      __builtin_amdgcn_s_setprio(1);
#pragma unroll
      for (int mi = 0; mi < 4; ++mi) {
#pragma unroll
        for (int ni = 0; ni < 4; ++ni)
          o[mi][ni] = __builtin_amdgcn_mfma_f32_16x16x32_bf16(pf[mi], vf[ni], o[mi][ni], 0, 0, 0);
        ol[mi] = __builtin_amdgcn_mfma_f32_16x16x32_bf16(pf[mi], ones, ol[mi], 0, 0, 0);
      }
      __builtin_amdgcn_s_setprio(0);
    }

    // end-of-tile barrier: all waves done with buf[cur]; vmcnt(0) drain lands
    // after a full compute phase -> prefetch latency hidden.
    __syncthreads();
  }

  // epilogue: ol[mi][r] = l for query mi*16+quad*4+r (uniform across l15)
  int b = bh >> 4, h = bh & 15;
#pragma unroll
  for (int mi = 0; mi < 4; ++mi) {
    float rl[4];
#pragma unroll
    for (int r = 0; r < 4; ++r) rl[r] = 1.0f / ol[mi][r];
#pragma unroll
    for (int ni = 0; ni < 4; ++ni) {
      int col = h * 64 + ni * 16 + l15;
#pragma unroll
      for (int r = 0; r < 4; ++r) {
        int q = q0 + w * 64 + mi * 16 + quad * 4 + r;
        ctx[(size_t)(b * 2048 + q) * 1024 + col] = fast_bf16(o[mi][ni][r] * rl[r]);
      }
    }
  }
}

extern "C" void kernel_launch(void* const* d_in, const int* in_sizes, int n_in,
                              void* d_out, int out_size, void* d_ws, size_t ws_size,
                              hipStream_t stream) {
  const float* x  = (const float*)d_in[0];
  const float* Wq = (const float*)d_in[1];
  const float* bq = (const float*)d_in[2];
  const float* Wk = (const float*)d_in[3];
  const float* bk = (const float*)d_in[4];
  const float* Wv = (const float*)d_in[5];
  const float* bv = (const float*)d_in[6];
  const float* Wo = (const float*)d_in[7];
  const float* bo = (const float*)d_in[8];
  float* out = (float*)d_out;

  char* ws = (char*)d_ws;
  const size_t MB = 1048576;
  bf16* xb  = (bf16*)(ws);             // 16 MB: x bf16 [8192][1024]
  bf16* Wt  = (bf16*)(ws + 16 * MB);   //  6 MB: Wqkv^T [3072][1024]
  bf16* Wot = (bf16*)(ws + 22 * MB);   //  2 MB: Wo^T   [1024][1024]
  bf16* Qb  = (bf16*)(ws + 24 * MB);   // 16 MB: Q [64][2048][64] (pre-scaled by log2e/8)
  bf16* Kb  = (bf16*)(ws + 40 * MB);   // 16 MB: K [64][2048][64]
  bf16* Vtb = (bf16*)(ws + 56 * MB);   // 16 MB: V^T [64][64][2048]
  bf16* Cx  = (bf16*)(ws + 72 * MB);   // 16 MB: ctx [8192][1024]

  prep<<<9216, 256, 0, stream>>>(x, xb, Wq, Wk, Wv, Wo, Wt, Wot);
  gemm_qkv<<<768, 512, 0, stream>>>(xb, Wt, bq, bk, bv, Qb, Kb, Vtb);
  attn<<<dim3(64, 8, 1), 256, 0, stream>>>(Qb, Kb, Vtb, Cx);
  gemm_out<<<256, 512, 0, stream>>>(Cx, Wot, bo, out);
}